// Round 1
// baseline (607.734 us; speedup 1.0000x reference)
//
#include <hip/hip_runtime.h>
#include <hip/hip_bf16.h>

#define B_SZ   2
#define LSEQ   4096
#define DMODEL 256
#define DINNER 512
#define NSTATE 16
#define CL     32
#define NCH    (LSEQ/CL)   // 128

// ---------------- LayerNorm: one wave (64 lanes) per 256-float row ----------
__global__ __launch_bounds__(256) void ln_kernel(
    const float* __restrict__ in, const float* __restrict__ w,
    const float* __restrict__ b, float* __restrict__ out, int rows)
{
  int wv = threadIdx.x >> 6, lane = threadIdx.x & 63;
  int row = blockIdx.x * 4 + wv;
  if (row >= rows) return;
  const float4* rp = reinterpret_cast<const float4*>(in) + (size_t)row * 64;
  float4 v = rp[lane];
  float s  = v.x + v.y + v.z + v.w;
  float sq = v.x*v.x + v.y*v.y + v.z*v.z + v.w*v.w;
  #pragma unroll
  for (int off = 32; off; off >>= 1) {
    s  += __shfl_xor(s,  off);
    sq += __shfl_xor(sq, off);
  }
  float mu  = s * (1.f/256.f);
  float var = sq * (1.f/256.f) - mu*mu;
  float rs  = rsqrtf(var + 1e-5f);
  float4 wv4 = reinterpret_cast<const float4*>(w)[lane];
  float4 bv4 = reinterpret_cast<const float4*>(b)[lane];
  float4 o;
  o.x = (v.x-mu)*rs*wv4.x + bv4.x;
  o.y = (v.y-mu)*rs*wv4.y + bv4.y;
  o.z = (v.z-mu)*rs*wv4.z + bv4.z;
  o.w = (v.w-mu)*rs*wv4.w + bv4.w;
  reinterpret_cast<float4*>(out)[(size_t)row * 64 + lane] = o;
}

// ---------------- fp32 tiled GEMM: C(M,N) = A(M,K) * W(N,K)^T  --------------
enum { EPI_NONE = 0, EPI_SKIPX = 1, EPI_BIAS = 2 };

template<int BM, int BN, int BK, int TM, int TN, int EPI>
__global__ __launch_bounds__(256) void gemm_nt(
    const float* __restrict__ A, const float* __restrict__ W,
    float* __restrict__ C, int M, int N, int K,
    const float* __restrict__ X, const float* __restrict__ sscale,
    const float* __restrict__ bias)
{
  __shared__ float As[BK][BM];
  __shared__ float Ws[BK][BN];
  constexpr int NTX = BN / TN;
  const int tid = threadIdx.x;
  const int tx = tid % NTX;
  const int ty = tid / NTX;
  const int bm = blockIdx.x * BM;
  const int bn = blockIdx.y * BN;

  float acc[TM][TN];
  #pragma unroll
  for (int i = 0; i < TM; i++)
    #pragma unroll
    for (int j = 0; j < TN; j++) acc[i][j] = 0.f;

  constexpr int KQ = BK / 4;
  for (int k0 = 0; k0 < K; k0 += BK) {
    for (int q = tid; q < BM * KQ; q += 256) {
      int row = q / KQ, kq = q % KQ;
      float4 v = *reinterpret_cast<const float4*>(A + (size_t)(bm + row) * K + k0 + kq*4);
      As[kq*4+0][row] = v.x; As[kq*4+1][row] = v.y;
      As[kq*4+2][row] = v.z; As[kq*4+3][row] = v.w;
    }
    for (int q = tid; q < BN * KQ; q += 256) {
      int row = q / KQ, kq = q % KQ;
      float4 v = *reinterpret_cast<const float4*>(W + (size_t)(bn + row) * K + k0 + kq*4);
      Ws[kq*4+0][row] = v.x; Ws[kq*4+1][row] = v.y;
      Ws[kq*4+2][row] = v.z; Ws[kq*4+3][row] = v.w;
    }
    __syncthreads();
    #pragma unroll
    for (int kk = 0; kk < BK; kk++) {
      float a[TM], bv[TN];
      #pragma unroll
      for (int i = 0; i < TM/4; i++) {
        float4 t = *reinterpret_cast<const float4*>(&As[kk][ty*TM + 4*i]);
        a[4*i] = t.x; a[4*i+1] = t.y; a[4*i+2] = t.z; a[4*i+3] = t.w;
      }
      if constexpr (TN % 4 == 0) {
        #pragma unroll
        for (int j = 0; j < TN/4; j++) {
          float4 t = *reinterpret_cast<const float4*>(&Ws[kk][tx*TN + 4*j]);
          bv[4*j] = t.x; bv[4*j+1] = t.y; bv[4*j+2] = t.z; bv[4*j+3] = t.w;
        }
      } else {
        #pragma unroll
        for (int j = 0; j < TN; j++) bv[j] = Ws[kk][tx*TN + j];
      }
      #pragma unroll
      for (int i = 0; i < TM; i++)
        #pragma unroll
        for (int j = 0; j < TN; j++)
          acc[i][j] += a[i] * bv[j];
    }
    __syncthreads();
  }

  float sv = 0.f;
  if constexpr (EPI == EPI_SKIPX) sv = sscale[0];

  #pragma unroll
  for (int i = 0; i < TM; i++) {
    size_t row = (size_t)bm + ty*TM + i;
    if constexpr (TN % 4 == 0) {
      #pragma unroll
      for (int j4 = 0; j4 < TN/4; j4++) {
        int col = bn + tx*TN + j4*4;
        float4 o;
        o.x = acc[i][j4*4+0]; o.y = acc[i][j4*4+1];
        o.z = acc[i][j4*4+2]; o.w = acc[i][j4*4+3];
        if constexpr (EPI == EPI_SKIPX) {
          float4 xv = *reinterpret_cast<const float4*>(X + row * N + col);
          o.x += sv*xv.x; o.y += sv*xv.y; o.z += sv*xv.z; o.w += sv*xv.w;
        } else if constexpr (EPI == EPI_BIAS) {
          float4 bb = *reinterpret_cast<const float4*>(bias + col);
          o.x += bb.x; o.y += bb.y; o.z += bb.z; o.w += bb.w;
        }
        *reinterpret_cast<float4*>(C + row * N + col) = o;
      }
    } else {
      #pragma unroll
      for (int j = 0; j < TN; j++) {
        int col = bn + tx*TN + j;
        C[row * N + col] = acc[i][j];
      }
    }
  }
}

// ---------------- depthwise causal conv (k=4) + SiLU ------------------------
__global__ __launch_bounds__(256) void conv_silu_kernel(
    const float* __restrict__ xz, const float* __restrict__ cw,
    const float* __restrict__ cb, float* __restrict__ xc)
{
  int idx = blockIdx.x * 256 + threadIdx.x;   // B*L*128
  int d4 = (idx & 127) << 2;
  int bt = idx >> 7;
  int t  = bt & (LSEQ - 1);
  int b  = bt >> 12;
  float a0 = cb[d4], a1 = cb[d4+1], a2 = cb[d4+2], a3 = cb[d4+3];
  float4 w0 = *reinterpret_cast<const float4*>(&cw[(d4+0)*4]);
  float4 w1 = *reinterpret_cast<const float4*>(&cw[(d4+1)*4]);
  float4 w2 = *reinterpret_cast<const float4*>(&cw[(d4+2)*4]);
  float4 w3 = *reinterpret_cast<const float4*>(&cw[(d4+3)*4]);
  const float* wp0 = (const float*)&w0;
  const float* wp1 = (const float*)&w1;
  const float* wp2 = (const float*)&w2;
  const float* wp3 = (const float*)&w3;
  #pragma unroll
  for (int j = 0; j < 4; j++) {
    int tt = t - 3 + j;
    if (tt >= 0) {
      float4 xv = *reinterpret_cast<const float4*>(&xz[((size_t)b*LSEQ + tt)*1024 + d4]);
      a0 += wp0[j]*xv.x; a1 += wp1[j]*xv.y; a2 += wp2[j]*xv.z; a3 += wp3[j]*xv.w;
    }
  }
  float4 o;
  o.x = a0 / (1.f + __expf(-a0));
  o.y = a1 / (1.f + __expf(-a1));
  o.z = a2 / (1.f + __expf(-a2));
  o.w = a3 / (1.f + __expf(-a3));
  *reinterpret_cast<float4*>(&xc[((size_t)b*LSEQ + t)*512 + d4]) = o;
}

// ---------------- dt_proj (K=16) + softplus ---------------------------------
__global__ __launch_bounds__(256) void dtproj_kernel(
    const float* __restrict__ dbc, const float* __restrict__ dpw,
    const float* __restrict__ dpb, float* __restrict__ delta)
{
  int tid = threadIdx.x;
  size_t row = (size_t)blockIdx.x * 2 + (tid >> 7);
  int d0 = (tid & 127) << 2;
  const float4* dt = reinterpret_cast<const float4*>(dbc + row * 48);
  float4 t0 = dt[0], t1 = dt[1], t2 = dt[2], t3 = dt[3];
  float4 out;
  float* op = (float*)&out;
  #pragma unroll
  for (int dd = 0; dd < 4; dd++) {
    int d = d0 + dd;
    const float4* wr = reinterpret_cast<const float4*>(&dpw[d*16]);
    float4 w0 = wr[0], w1 = wr[1], w2 = wr[2], w3 = wr[3];
    float acc = dpb[d];
    acc += t0.x*w0.x + t0.y*w0.y + t0.z*w0.z + t0.w*w0.w;
    acc += t1.x*w1.x + t1.y*w1.y + t1.z*w1.z + t1.w*w1.w;
    acc += t2.x*w2.x + t2.y*w2.y + t2.z*w2.z + t2.w*w2.w;
    acc += t3.x*w3.x + t3.y*w3.y + t3.z*w3.z + t3.w*w3.w;
    op[dd] = fmaxf(acc, 0.f) + log1pf(__expf(-fabsf(acc)));
  }
  *reinterpret_cast<float4*>(&delta[row * 512 + d0]) = out;
}

// ---------------- selective scan, chunked 3-phase ---------------------------
// thread = (b, chunk, d); lane-adjacent threads are d-adjacent (coalesced)
__global__ __launch_bounds__(256) void scanA_kernel(
    const float* __restrict__ delta, const float* __restrict__ xc,
    const float* __restrict__ dbc, const float* __restrict__ A_log,
    float* __restrict__ hloc, float* __restrict__ Ssum)
{
  int idx = blockIdx.x * 256 + threadIdx.x;  // B*NCH*512
  int d = idx & 511;
  int c = (idx >> 9) & (NCH - 1);
  int b = idx >> 16;
  float Arow[16];
  #pragma unroll
  for (int n = 0; n < 16; n++) Arow[n] = -__expf(A_log[d*16 + n]);
  float h[16];
  #pragma unroll
  for (int n = 0; n < 16; n++) h[n] = 0.f;
  float S = 0.f;
  size_t tbase = (size_t)b * LSEQ + (size_t)c * CL;
  for (int t = 0; t < CL; t++) {
    size_t r = tbase + t;
    float dl = delta[r*512 + d];
    float u  = xc[r*512 + d];
    float du = dl * u;
    S += dl;
    const float4* Bp = reinterpret_cast<const float4*>(dbc + r*48 + 16);
    float4 B0 = Bp[0], B1 = Bp[1], B2 = Bp[2], B3 = Bp[3];
    float Bv[16] = {B0.x,B0.y,B0.z,B0.w, B1.x,B1.y,B1.z,B1.w,
                    B2.x,B2.y,B2.z,B2.w, B3.x,B3.y,B3.z,B3.w};
    #pragma unroll
    for (int n = 0; n < 16; n++) {
      float dA = __expf(dl * Arow[n]);
      h[n] = dA * h[n] + du * Bv[n];
    }
  }
  size_t o = ((size_t)b*512 + d) * NCH + c;
  #pragma unroll
  for (int n = 0; n < 16; n++) hloc[o*16 + n] = h[n];
  Ssum[o] = S;
}

__global__ __launch_bounds__(256) void scanMid_kernel(
    const float* __restrict__ hloc, const float* __restrict__ Ssum,
    const float* __restrict__ A_log, float* __restrict__ henter)
{
  int idx = blockIdx.x * 256 + threadIdx.x;  // 1024
  if (idx >= B_SZ * 512) return;
  int d = idx & 511;
  float Arow[16];
  #pragma unroll
  for (int n = 0; n < 16; n++) Arow[n] = -__expf(A_log[d*16 + n]);
  float h[16];
  #pragma unroll
  for (int n = 0; n < 16; n++) h[n] = 0.f;
  size_t base = (size_t)idx * NCH;
  for (int c = 0; c < NCH; c++) {
    #pragma unroll
    for (int n = 0; n < 16; n++) henter[(base + c)*16 + n] = h[n];
    float S = Ssum[base + c];
    #pragma unroll
    for (int n = 0; n < 16; n++)
      h[n] = __expf(S * Arow[n]) * h[n] + hloc[(base + c)*16 + n];
  }
}

__global__ __launch_bounds__(256) void scanB_kernel(
    const float* __restrict__ delta, float* __restrict__ xc,
    const float* __restrict__ dbc, const float* __restrict__ A_log,
    const float* __restrict__ henter, const float* __restrict__ Dskip,
    const float* __restrict__ xz)
{
  int idx = blockIdx.x * 256 + threadIdx.x;
  int d = idx & 511;
  int c = (idx >> 9) & (NCH - 1);
  int b = idx >> 16;
  float Arow[16];
  #pragma unroll
  for (int n = 0; n < 16; n++) Arow[n] = -__expf(A_log[d*16 + n]);
  size_t o = ((size_t)b*512 + d) * NCH + c;
  float h[16];
  #pragma unroll
  for (int n = 0; n < 16; n++) h[n] = henter[o*16 + n];
  float Dsk = Dskip[d];
  size_t tbase = (size_t)b * LSEQ + (size_t)c * CL;
  for (int t = 0; t < CL; t++) {
    size_t r = tbase + t;
    float dl = delta[r*512 + d];
    float u  = xc[r*512 + d];
    float du = dl * u;
    const float4* Bp = reinterpret_cast<const float4*>(dbc + r*48 + 16);
    const float4* Cp = reinterpret_cast<const float4*>(dbc + r*48 + 32);
    float4 B0 = Bp[0], B1 = Bp[1], B2 = Bp[2], B3 = Bp[3];
    float4 C0 = Cp[0], C1 = Cp[1], C2 = Cp[2], C3 = Cp[3];
    float Bv[16] = {B0.x,B0.y,B0.z,B0.w, B1.x,B1.y,B1.z,B1.w,
                    B2.x,B2.y,B2.z,B2.w, B3.x,B3.y,B3.z,B3.w};
    float Cv[16] = {C0.x,C0.y,C0.z,C0.w, C1.x,C1.y,C1.z,C1.w,
                    C2.x,C2.y,C2.z,C2.w, C3.x,C3.y,C3.z,C3.w};
    float y = 0.f;
    #pragma unroll
    for (int n = 0; n < 16; n++) {
      float dA = __expf(dl * Arow[n]);
      h[n] = dA * h[n] + du * Bv[n];
      y += h[n] * Cv[n];
    }
    y += u * Dsk;
    float z = xz[r*1024 + 512 + d];
    float sig = 1.f / (1.f + __expf(-z));
    xc[r*512 + d] = y * z * sig;   // in-place gated output
  }
}

// ---------------- launch ----------------------------------------------------
extern "C" void kernel_launch(void* const* d_in, const int* in_sizes, int n_in,
                              void* d_out, int out_size, void* d_ws, size_t ws_size,
                              hipStream_t stream)
{
  const float* x      = (const float*)d_in[0];
  const float* ln_w   = (const float*)d_in[1];
  const float* ln_b   = (const float*)d_in[2];
  const float* inW    = (const float*)d_in[3];
  const float* convW  = (const float*)d_in[4];
  const float* convB  = (const float*)d_in[5];
  const float* xprojW = (const float*)d_in[6];
  const float* dtW    = (const float*)d_in[7];
  const float* dtB    = (const float*)d_in[8];
  const float* A_log  = (const float*)d_in[9];
  const float* Dskip  = (const float*)d_in[10];
  const float* outW   = (const float*)d_in[11];
  const float* projW  = (const float*)d_in[12];
  const float* projB  = (const float*)d_in[13];
  const float* skip   = (const float*)d_in[14];
  float* out = (float*)d_out;

  const size_t BL = (size_t)B_SZ * LSEQ;   // 8192
  float* ws    = (float*)d_ws;
  float* xn    = ws;                        // BL*256
  float* xz    = xn    + BL*256;            // BL*1024
  float* xc    = xz    + BL*1024;           // BL*512
  float* dbc   = xc    + BL*512;            // BL*48
  float* delta = dbc   + BL*48;             // BL*512
  float* hloc  = delta + BL*512;            // B*512*NCH*16
  float* henter= hloc  + (size_t)B_SZ*512*NCH*16;
  float* Ssum  = henter+ (size_t)B_SZ*512*NCH*16;  // B*512*NCH
  float* xm    = xn;   // reuse (xn dead after in_proj)
  float* xn2   = xz;   // reuse (xz dead after scanB)

  ln_kernel<<<BL/4, 256, 0, stream>>>(x, ln_w, ln_b, xn, (int)BL);

  gemm_nt<128,128,32,8,8,EPI_NONE><<<dim3(BL/128, 1024/128), 256, 0, stream>>>(
      xn, inW, xz, (int)BL, 1024, 256, nullptr, nullptr, nullptr);

  conv_silu_kernel<<<(B_SZ*LSEQ*128)/256, 256, 0, stream>>>(xz, convW, convB, xc);

  gemm_nt<64,48,32,4,3,EPI_NONE><<<dim3(BL/64, 1), 256, 0, stream>>>(
      xc, xprojW, dbc, (int)BL, 48, 512, nullptr, nullptr, nullptr);

  dtproj_kernel<<<BL/2, 256, 0, stream>>>(dbc, dtW, dtB, delta);

  scanA_kernel<<<(B_SZ*NCH*512)/256, 256, 0, stream>>>(delta, xc, dbc, A_log, hloc, Ssum);
  scanMid_kernel<<<4, 256, 0, stream>>>(hloc, Ssum, A_log, henter);
  scanB_kernel<<<(B_SZ*NCH*512)/256, 256, 0, stream>>>(delta, xc, dbc, A_log, henter, Dskip, xz);

  gemm_nt<64,64,32,4,4,EPI_SKIPX><<<dim3(BL/64, 256/64), 256, 0, stream>>>(
      xc, outW, xm, (int)BL, 256, 512, x, skip, nullptr);

  ln_kernel<<<BL/4, 256, 0, stream>>>(xm, ln_w, ln_b, xn2, (int)BL);

  gemm_nt<64,64,32,4,4,EPI_BIAS><<<dim3(BL/64, 256/64), 256, 0, stream>>>(
      xn2, projW, out, (int)BL, 256, 256, nullptr, nullptr, projB);
}

// Round 2
// 396.413 us; speedup vs baseline: 1.5331x; 1.5331x over previous
//
#include <hip/hip_runtime.h>
#include <hip/hip_bf16.h>

#define B_SZ   2
#define LSEQ   4096
#define NCH    128
#define CL     32

typedef __attribute__((ext_vector_type(8))) short short8;
typedef __attribute__((ext_vector_type(4))) float f32x4;

__device__ __forceinline__ unsigned short f2bf(float f) {
  union { float f; unsigned u; } x; x.f = f;
  unsigned r = x.u + 0x7fffu + ((x.u >> 16) & 1u);
  return (unsigned short)(r >> 16);
}

// ---------------- weight fp32 -> bf16 convert -------------------------------
__global__ __launch_bounds__(256) void f2bf4_kernel(
    const float* __restrict__ in, unsigned short* __restrict__ out)
{
  int i = (blockIdx.x * 256 + threadIdx.x) * 4;
  float4 v = *reinterpret_cast<const float4*>(in + i);
  ushort4 o;
  o.x = f2bf(v.x); o.y = f2bf(v.y); o.z = f2bf(v.z); o.w = f2bf(v.w);
  *reinterpret_cast<ushort4*>(out + i) = o;
}

// ---------------- LayerNorm: one wave per 256-float row, bf16 out -----------
__global__ __launch_bounds__(256) void ln_bf_kernel(
    const float* __restrict__ in, const float* __restrict__ w,
    const float* __restrict__ b, unsigned short* __restrict__ out)
{
  int wv = threadIdx.x >> 6, lane = threadIdx.x & 63;
  size_t row = (size_t)blockIdx.x * 4 + wv;
  float4 v = reinterpret_cast<const float4*>(in)[row * 64 + lane];
  float s  = v.x + v.y + v.z + v.w;
  float sq = v.x*v.x + v.y*v.y + v.z*v.z + v.w*v.w;
  #pragma unroll
  for (int off = 32; off; off >>= 1) {
    s  += __shfl_xor(s,  off);
    sq += __shfl_xor(sq, off);
  }
  float mu  = s * (1.f/256.f);
  float var = sq * (1.f/256.f) - mu*mu;
  float rs  = rsqrtf(var + 1e-5f);
  float4 wv4 = reinterpret_cast<const float4*>(w)[lane];
  float4 bv4 = reinterpret_cast<const float4*>(b)[lane];
  ushort4 o;
  o.x = f2bf((v.x-mu)*rs*wv4.x + bv4.x);
  o.y = f2bf((v.y-mu)*rs*wv4.y + bv4.y);
  o.z = f2bf((v.z-mu)*rs*wv4.z + bv4.z);
  o.w = f2bf((v.w-mu)*rs*wv4.w + bv4.w);
  reinterpret_cast<ushort4*>(out)[row * 64 + lane] = o;
}

// ---------------- bf16 MFMA GEMM: C(M,N) = A(M,K) * W(N,K)^T ----------------
enum { EPI_NONE = 0, EPI_SKIPX = 1, EPI_BIAS = 2 };

template<int BM, int BN, int EPI>
__global__ __launch_bounds__(256) void gemm_mfma(
    const unsigned short* __restrict__ A, const unsigned short* __restrict__ W,
    float* __restrict__ C, int M, int N, int K,
    const float* __restrict__ X, const float* __restrict__ sscale,
    const float* __restrict__ bias)
{
  constexpr int BK = 32;
  constexpr int WM = BM / 2, WN = BN / 2;
  constexpr int AM = WM / 16, BF = WN / 16;
  constexpr int ALD = BM / 64, BLD = BN / 64;   // 16B loads per thread
  __shared__ __align__(16) unsigned short As[BM * BK];
  __shared__ __align__(16) unsigned short Ws[BN * BK];
  const int tid = threadIdx.x;
  const int lane = tid & 63, wid = tid >> 6;
  const int wr = wid >> 1, wc = wid & 1;        // 2x2 waves
  const int bm = blockIdx.x * BM, bn = blockIdx.y * BN;

  f32x4 acc[AM][BF] = {};

  for (int kt = 0; kt < K; kt += BK) {
    uint4 ar[ALD], br[BLD];
    #pragma unroll
    for (int c = 0; c < ALD; c++) {
      int e = (c * 256 + tid) * 8;
      ar[c] = *reinterpret_cast<const uint4*>(A + (size_t)(bm + (e >> 5)) * K + kt + (e & 31));
    }
    #pragma unroll
    for (int c = 0; c < BLD; c++) {
      int e = (c * 256 + tid) * 8;
      br[c] = *reinterpret_cast<const uint4*>(W + (size_t)(bn + (e >> 5)) * K + kt + (e & 31));
    }
    __syncthreads();   // previous tile's LDS reads done
    #pragma unroll
    for (int c = 0; c < ALD; c++) {
      int e = (c * 256 + tid) * 8;
      *reinterpret_cast<uint4*>(&As[e]) = ar[c];
    }
    #pragma unroll
    for (int c = 0; c < BLD; c++) {
      int e = (c * 256 + tid) * 8;
      *reinterpret_cast<uint4*>(&Ws[e]) = br[c];
    }
    __syncthreads();

    short8 af[AM], bfr[BF];
    #pragma unroll
    for (int i = 0; i < AM; i++)
      af[i] = *reinterpret_cast<const short8*>(
          &As[(wr * WM + i * 16 + (lane & 15)) * BK + (lane >> 4) * 8]);
    #pragma unroll
    for (int j = 0; j < BF; j++)
      bfr[j] = *reinterpret_cast<const short8*>(
          &Ws[(wc * WN + j * 16 + (lane & 15)) * BK + (lane >> 4) * 8]);
    #pragma unroll
    for (int i = 0; i < AM; i++)
      #pragma unroll
      for (int j = 0; j < BF; j++)
        acc[i][j] = __builtin_amdgcn_mfma_f32_16x16x32_bf16(af[i], bfr[j], acc[i][j], 0, 0, 0);
  }

  float sv = 0.f;
  if constexpr (EPI == EPI_SKIPX) sv = sscale[0];

  #pragma unroll
  for (int i = 0; i < AM; i++) {
    #pragma unroll
    for (int j = 0; j < BF; j++) {
      int row0 = bm + wr * WM + i * 16 + ((lane >> 4) << 2);
      int col  = bn + wc * WN + j * 16 + (lane & 15);
      #pragma unroll
      for (int r = 0; r < 4; r++) {
        float v = acc[i][j][r];
        size_t off = (size_t)(row0 + r) * N + col;
        if constexpr (EPI == EPI_SKIPX) v += sv * X[off];
        if constexpr (EPI == EPI_BIAS)  v += bias[col];
        C[off] = v;
      }
    }
  }
}

// ---------------- fp32 tiled GEMM (kept for x_proj, N=48) -------------------
template<int BM, int BN, int BK, int TM, int TN>
__global__ __launch_bounds__(256) void gemm_nt(
    const float* __restrict__ A, const float* __restrict__ W,
    float* __restrict__ C, int M, int N, int K)
{
  __shared__ float As[BK][BM];
  __shared__ float Ws[BK][BN];
  constexpr int NTX = BN / TN;
  const int tid = threadIdx.x;
  const int tx = tid % NTX;
  const int ty = tid / NTX;
  const int bm = blockIdx.x * BM;
  const int bn = blockIdx.y * BN;

  float acc[TM][TN];
  #pragma unroll
  for (int i = 0; i < TM; i++)
    #pragma unroll
    for (int j = 0; j < TN; j++) acc[i][j] = 0.f;

  constexpr int KQ = BK / 4;
  for (int k0 = 0; k0 < K; k0 += BK) {
    for (int q = tid; q < BM * KQ; q += 256) {
      int row = q / KQ, kq = q % KQ;
      float4 v = *reinterpret_cast<const float4*>(A + (size_t)(bm + row) * K + k0 + kq*4);
      As[kq*4+0][row] = v.x; As[kq*4+1][row] = v.y;
      As[kq*4+2][row] = v.z; As[kq*4+3][row] = v.w;
    }
    for (int q = tid; q < BN * KQ; q += 256) {
      int row = q / KQ, kq = q % KQ;
      float4 v = *reinterpret_cast<const float4*>(W + (size_t)(bn + row) * K + k0 + kq*4);
      Ws[kq*4+0][row] = v.x; Ws[kq*4+1][row] = v.y;
      Ws[kq*4+2][row] = v.z; Ws[kq*4+3][row] = v.w;
    }
    __syncthreads();
    #pragma unroll
    for (int kk = 0; kk < BK; kk++) {
      float a[TM], bv[TN];
      #pragma unroll
      for (int i = 0; i < TM/4; i++) {
        float4 t = *reinterpret_cast<const float4*>(&As[kk][ty*TM + 4*i]);
        a[4*i] = t.x; a[4*i+1] = t.y; a[4*i+2] = t.z; a[4*i+3] = t.w;
      }
      #pragma unroll
      for (int j = 0; j < TN; j++) bv[j] = Ws[kk][tx*TN + j];
      #pragma unroll
      for (int i = 0; i < TM; i++)
        #pragma unroll
        for (int j = 0; j < TN; j++)
          acc[i][j] += a[i] * bv[j];
    }
    __syncthreads();
  }
  #pragma unroll
  for (int i = 0; i < TM; i++) {
    size_t row = (size_t)bm + ty*TM + i;
    #pragma unroll
    for (int j = 0; j < TN; j++) {
      int col = bn + tx*TN + j;
      C[row * N + col] = acc[i][j];
    }
  }
}

// ---------------- depthwise causal conv (k=4) + SiLU ------------------------
__global__ __launch_bounds__(256) void conv_silu_kernel(
    const float* __restrict__ xz, const float* __restrict__ cw,
    const float* __restrict__ cb, float* __restrict__ xc)
{
  int idx = blockIdx.x * 256 + threadIdx.x;   // B*L*128
  int d4 = (idx & 127) << 2;
  int bt = idx >> 7;
  int t  = bt & (LSEQ - 1);
  int b  = bt >> 12;
  float a0 = cb[d4], a1 = cb[d4+1], a2 = cb[d4+2], a3 = cb[d4+3];
  float4 w0 = *reinterpret_cast<const float4*>(&cw[(d4+0)*4]);
  float4 w1 = *reinterpret_cast<const float4*>(&cw[(d4+1)*4]);
  float4 w2 = *reinterpret_cast<const float4*>(&cw[(d4+2)*4]);
  float4 w3 = *reinterpret_cast<const float4*>(&cw[(d4+3)*4]);
  const float* wp0 = (const float*)&w0;
  const float* wp1 = (const float*)&w1;
  const float* wp2 = (const float*)&w2;
  const float* wp3 = (const float*)&w3;
  #pragma unroll
  for (int j = 0; j < 4; j++) {
    int tt = t - 3 + j;
    if (tt >= 0) {
      float4 xv = *reinterpret_cast<const float4*>(&xz[((size_t)b*LSEQ + tt)*1024 + d4]);
      a0 += wp0[j]*xv.x; a1 += wp1[j]*xv.y; a2 += wp2[j]*xv.z; a3 += wp3[j]*xv.w;
    }
  }
  float4 o;
  o.x = a0 / (1.f + __expf(-a0));
  o.y = a1 / (1.f + __expf(-a1));
  o.z = a2 / (1.f + __expf(-a2));
  o.w = a3 / (1.f + __expf(-a3));
  *reinterpret_cast<float4*>(&xc[((size_t)b*LSEQ + t)*512 + d4]) = o;
}

// ---------------- dt_proj (K=16) + softplus ---------------------------------
__global__ __launch_bounds__(256) void dtproj_kernel(
    const float* __restrict__ dbc, const float* __restrict__ dpw,
    const float* __restrict__ dpb, float* __restrict__ delta)
{
  int tid = threadIdx.x;
  size_t row = (size_t)blockIdx.x * 2 + (tid >> 7);
  int d0 = (tid & 127) << 2;
  const float4* dt = reinterpret_cast<const float4*>(dbc + row * 48);
  float4 t0 = dt[0], t1 = dt[1], t2 = dt[2], t3 = dt[3];
  float4 out;
  float* op = (float*)&out;
  #pragma unroll
  for (int dd = 0; dd < 4; dd++) {
    int d = d0 + dd;
    const float4* wr = reinterpret_cast<const float4*>(&dpw[d*16]);
    float4 w0 = wr[0], w1 = wr[1], w2 = wr[2], w3 = wr[3];
    float acc = dpb[d];
    acc += t0.x*w0.x + t0.y*w0.y + t0.z*w0.z + t0.w*w0.w;
    acc += t1.x*w1.x + t1.y*w1.y + t1.z*w1.z + t1.w*w1.w;
    acc += t2.x*w2.x + t2.y*w2.y + t2.z*w2.z + t2.w*w2.w;
    acc += t3.x*w3.x + t3.y*w3.y + t3.z*w3.z + t3.w*w3.w;
    op[dd] = fmaxf(acc, 0.f) + log1pf(__expf(-fabsf(acc)));
  }
  *reinterpret_cast<float4*>(&delta[row * 512 + d0]) = out;
}

// ---------------- selective scan, chunked 3-phase ---------------------------
// layouts: hloc/henter[((c*B+b)*512+d)*16+n], Ssum[(c*B+b)*512+d]  (chunk-major)
__global__ __launch_bounds__(256) void scanA_kernel(
    const float* __restrict__ delta, const float* __restrict__ xc,
    const float* __restrict__ dbc, const float* __restrict__ A_log,
    float* __restrict__ hloc, float* __restrict__ Ssum)
{
  int idx = blockIdx.x * 256 + threadIdx.x;  // B*NCH*512
  int d = idx & 511;
  int c = (idx >> 9) & (NCH - 1);
  int b = idx >> 16;
  float Arow[16];
  #pragma unroll
  for (int n = 0; n < 16; n++) Arow[n] = -__expf(A_log[d*16 + n]);
  float h[16];
  #pragma unroll
  for (int n = 0; n < 16; n++) h[n] = 0.f;
  float S = 0.f;
  size_t tbase = (size_t)b * LSEQ + (size_t)c * CL;
  for (int t = 0; t < CL; t++) {
    size_t r = tbase + t;
    float dl = delta[r*512 + d];
    float u  = xc[r*512 + d];
    float du = dl * u;
    S += dl;
    const float4* Bp = reinterpret_cast<const float4*>(dbc + r*48 + 16);
    float4 B0 = Bp[0], B1 = Bp[1], B2 = Bp[2], B3 = Bp[3];
    float Bv[16] = {B0.x,B0.y,B0.z,B0.w, B1.x,B1.y,B1.z,B1.w,
                    B2.x,B2.y,B2.z,B2.w, B3.x,B3.y,B3.z,B3.w};
    #pragma unroll
    for (int n = 0; n < 16; n++) {
      float dA = __expf(dl * Arow[n]);
      h[n] = dA * h[n] + du * Bv[n];
    }
  }
  size_t o = ((size_t)c * B_SZ + b) * 512 + d;
  #pragma unroll
  for (int n = 0; n < 16; n++) hloc[o*16 + n] = h[n];
  Ssum[o] = S;
}

// one thread per (b,d,n) state component; fully coalesced over (d,n)
__global__ __launch_bounds__(256) void scanmid2_kernel(
    const float* __restrict__ hloc, const float* __restrict__ Ssum,
    const float* __restrict__ A_log, float* __restrict__ henter)
{
  int g = blockIdx.x * 256 + threadIdx.x;   // B*512*16 = 16384
  int n = g & 15, d = (g >> 4) & 511, b = g >> 13;
  float Ar = -__expf(A_log[d*16 + n]);
  float h = 0.f;
  #pragma unroll 4
  for (int c = 0; c < NCH; c++) {
    size_t idx = ((size_t)c * B_SZ + b) * 512 + d;
    henter[idx*16 + n] = h;
    h = __expf(Ssum[idx] * Ar) * h + hloc[idx*16 + n];
  }
}

__global__ __launch_bounds__(256) void scanB_kernel(
    const float* __restrict__ delta, const float* __restrict__ xc,
    const float* __restrict__ dbc, const float* __restrict__ A_log,
    const float* __restrict__ henter, const float* __restrict__ Dskip,
    const float* __restrict__ xz, unsigned short* __restrict__ y_bf)
{
  int idx = blockIdx.x * 256 + threadIdx.x;
  int d = idx & 511;
  int c = (idx >> 9) & (NCH - 1);
  int b = idx >> 16;
  float Arow[16];
  #pragma unroll
  for (int n = 0; n < 16; n++) Arow[n] = -__expf(A_log[d*16 + n]);
  size_t o = ((size_t)c * B_SZ + b) * 512 + d;
  float h[16];
  #pragma unroll
  for (int n = 0; n < 16; n++) h[n] = henter[o*16 + n];
  float Dsk = Dskip[d];
  size_t tbase = (size_t)b * LSEQ + (size_t)c * CL;
  for (int t = 0; t < CL; t++) {
    size_t r = tbase + t;
    float dl = delta[r*512 + d];
    float u  = xc[r*512 + d];
    float du = dl * u;
    const float4* Bp = reinterpret_cast<const float4*>(dbc + r*48 + 16);
    const float4* Cp = reinterpret_cast<const float4*>(dbc + r*48 + 32);
    float4 B0 = Bp[0], B1 = Bp[1], B2 = Bp[2], B3 = Bp[3];
    float4 C0 = Cp[0], C1 = Cp[1], C2 = Cp[2], C3 = Cp[3];
    float Bv[16] = {B0.x,B0.y,B0.z,B0.w, B1.x,B1.y,B1.z,B1.w,
                    B2.x,B2.y,B2.z,B2.w, B3.x,B3.y,B3.z,B3.w};
    float Cv[16] = {C0.x,C0.y,C0.z,C0.w, C1.x,C1.y,C1.z,C1.w,
                    C2.x,C2.y,C2.z,C2.w, C3.x,C3.y,C3.z,C3.w};
    float y = 0.f;
    #pragma unroll
    for (int n = 0; n < 16; n++) {
      float dA = __expf(dl * Arow[n]);
      h[n] = dA * h[n] + du * Bv[n];
      y += h[n] * Cv[n];
    }
    y += u * Dsk;
    float z = xz[r*1024 + 512 + d];
    float sig = 1.f / (1.f + __expf(-z));
    y_bf[r*512 + d] = f2bf(y * z * sig);
  }
}

// ---------------- launch ----------------------------------------------------
extern "C" void kernel_launch(void* const* d_in, const int* in_sizes, int n_in,
                              void* d_out, int out_size, void* d_ws, size_t ws_size,
                              hipStream_t stream)
{
  const float* x      = (const float*)d_in[0];
  const float* ln_w   = (const float*)d_in[1];
  const float* ln_b   = (const float*)d_in[2];
  const float* inW    = (const float*)d_in[3];
  const float* convW  = (const float*)d_in[4];
  const float* convB  = (const float*)d_in[5];
  const float* xprojW = (const float*)d_in[6];
  const float* dtW    = (const float*)d_in[7];
  const float* dtB    = (const float*)d_in[8];
  const float* A_log  = (const float*)d_in[9];
  const float* Dskip  = (const float*)d_in[10];
  const float* outW   = (const float*)d_in[11];
  const float* projW  = (const float*)d_in[12];
  const float* projB  = (const float*)d_in[13];
  const float* skip   = (const float*)d_in[14];
  float* out = (float*)d_out;

  const size_t BL = (size_t)B_SZ * LSEQ;   // 8192
  char* p = (char*)d_ws;
  unsigned short* xn_bf = (unsigned short*)p;  p += BL*256*2;      // bf16, reused as xn2_bf
  float* xz     = (float*)p;                   p += BL*1024*4;
  float* xc     = (float*)p;                   p += BL*512*4;
  float* dbc    = (float*)p;                   p += BL*48*4;
  float* delta  = (float*)p;                   p += BL*512*4;
  float* hloc   = (float*)p;                   p += (size_t)B_SZ*512*NCH*16*4;
  float* henter = (float*)p;                   p += (size_t)B_SZ*512*NCH*16*4;
  float* Ssum   = (float*)p;                   p += (size_t)B_SZ*512*NCH*4;
  unsigned short* y_bf = (unsigned short*)p;   p += BL*512*2;
  unsigned short* inW_bf  = (unsigned short*)p; p += 1024*256*2;
  unsigned short* outW_bf = (unsigned short*)p; p += 256*512*2;
  unsigned short* projW_bf= (unsigned short*)p; p += 256*256*2;
  float* xm = hloc;                 // hloc dead after scanmid2; xm born at out_proj
  unsigned short* xn2_bf = xn_bf;   // xn_bf dead after in_proj

  // weight conversions (each thread handles 4 floats)
  f2bf4_kernel<<<1024*256/1024, 256, 0, stream>>>(inW,  inW_bf);
  f2bf4_kernel<<<256*512/1024, 256, 0, stream>>>(outW, outW_bf);
  f2bf4_kernel<<<256*256/1024, 256, 0, stream>>>(projW, projW_bf);

  ln_bf_kernel<<<BL/4, 256, 0, stream>>>(x, ln_w, ln_b, xn_bf);

  gemm_mfma<128,128,EPI_NONE><<<dim3(BL/128, 1024/128), 256, 0, stream>>>(
      xn_bf, inW_bf, xz, (int)BL, 1024, 256, nullptr, nullptr, nullptr);

  conv_silu_kernel<<<(B_SZ*LSEQ*128)/256, 256, 0, stream>>>(xz, convW, convB, xc);

  gemm_nt<64,48,32,4,3><<<dim3(BL/64, 1), 256, 0, stream>>>(
      xc, xprojW, dbc, (int)BL, 48, 512);

  dtproj_kernel<<<BL/2, 256, 0, stream>>>(dbc, dtW, dtB, delta);

  scanA_kernel<<<(B_SZ*NCH*512)/256, 256, 0, stream>>>(delta, xc, dbc, A_log, hloc, Ssum);
  scanmid2_kernel<<<B_SZ*512*16/256, 256, 0, stream>>>(hloc, Ssum, A_log, henter);
  scanB_kernel<<<(B_SZ*NCH*512)/256, 256, 0, stream>>>(delta, xc, dbc, A_log, henter, Dskip, xz, y_bf);

  gemm_mfma<128,64,EPI_SKIPX><<<dim3(BL/128, 256/64), 256, 0, stream>>>(
      y_bf, outW_bf, xm, (int)BL, 256, 512, x, skip, nullptr);

  ln_bf_kernel<<<BL/4, 256, 0, stream>>>(xm, ln_w, ln_b, xn2_bf);

  gemm_mfma<128,64,EPI_BIAS><<<dim3(BL/128, 256/64), 256, 0, stream>>>(
      xn2_bf, projW_bf, out, (int)BL, 256, 256, nullptr, nullptr, projB);
}

// Round 3
// 337.333 us; speedup vs baseline: 1.8016x; 1.1751x over previous
//
#include <hip/hip_runtime.h>
#include <hip/hip_bf16.h>

#define B_SZ   2
#define LSEQ   4096
#define NCH    256
#define CL     16

typedef __attribute__((ext_vector_type(8))) short short8;
typedef __attribute__((ext_vector_type(4))) float f32x4;

__device__ __forceinline__ unsigned short f2bf(float f) {
  union { float f; unsigned u; } x; x.f = f;
  unsigned r = x.u + 0x7fffu + ((x.u >> 16) & 1u);
  return (unsigned short)(r >> 16);
}

// ---------------- weight fp32 -> bf16 convert -------------------------------
__global__ __launch_bounds__(256) void f2bf4_kernel(
    const float* __restrict__ in, unsigned short* __restrict__ out)
{
  int i = (blockIdx.x * 256 + threadIdx.x) * 4;
  float4 v = *reinterpret_cast<const float4*>(in + i);
  ushort4 o;
  o.x = f2bf(v.x); o.y = f2bf(v.y); o.z = f2bf(v.z); o.w = f2bf(v.w);
  *reinterpret_cast<ushort4*>(out + i) = o;
}

// ---------------- LayerNorm: one wave per 256-float row, bf16 out -----------
__global__ __launch_bounds__(256) void ln_bf_kernel(
    const float* __restrict__ in, const float* __restrict__ w,
    const float* __restrict__ b, unsigned short* __restrict__ out)
{
  int wv = threadIdx.x >> 6, lane = threadIdx.x & 63;
  size_t row = (size_t)blockIdx.x * 4 + wv;
  float4 v = reinterpret_cast<const float4*>(in)[row * 64 + lane];
  float s  = v.x + v.y + v.z + v.w;
  float sq = v.x*v.x + v.y*v.y + v.z*v.z + v.w*v.w;
  #pragma unroll
  for (int off = 32; off; off >>= 1) {
    s  += __shfl_xor(s,  off);
    sq += __shfl_xor(sq, off);
  }
  float mu  = s * (1.f/256.f);
  float var = sq * (1.f/256.f) - mu*mu;
  float rs  = rsqrtf(var + 1e-5f);
  float4 wv4 = reinterpret_cast<const float4*>(w)[lane];
  float4 bv4 = reinterpret_cast<const float4*>(b)[lane];
  ushort4 o;
  o.x = f2bf((v.x-mu)*rs*wv4.x + bv4.x);
  o.y = f2bf((v.y-mu)*rs*wv4.y + bv4.y);
  o.z = f2bf((v.z-mu)*rs*wv4.z + bv4.z);
  o.w = f2bf((v.w-mu)*rs*wv4.w + bv4.w);
  reinterpret_cast<ushort4*>(out)[row * 64 + lane] = o;
}

// ---------------- bf16 MFMA GEMM: C(M,N) = A(M,K) * W(N,K)^T ----------------
enum { EPI_NONE = 0, EPI_SKIPX = 1, EPI_BIAS = 2 };

template<int BM, int BN, int EPI>
__global__ __launch_bounds__(256) void gemm_mfma(
    const unsigned short* __restrict__ A, const unsigned short* __restrict__ W,
    float* __restrict__ C, int M, int N, int K,
    const float* __restrict__ X, const float* __restrict__ sscale,
    const float* __restrict__ bias)
{
  constexpr int BK = 32;
  constexpr int WM = BM / 2, WN = BN / 2;
  constexpr int AM = WM / 16, BF = WN / 16;
  constexpr int ALD = BM / 64, BLD = BN / 64;
  __shared__ __align__(16) unsigned short As[BM * BK];
  __shared__ __align__(16) unsigned short Ws[BN * BK];
  const int tid = threadIdx.x;
  const int lane = tid & 63, wid = tid >> 6;
  const int wr = wid >> 1, wc = wid & 1;        // 2x2 waves
  const int bm = blockIdx.x * BM, bn = blockIdx.y * BN;

  f32x4 acc[AM][BF] = {};

  for (int kt = 0; kt < K; kt += BK) {
    uint4 ar[ALD], br[BLD];
    #pragma unroll
    for (int c = 0; c < ALD; c++) {
      int e = (c * 256 + tid) * 8;
      ar[c] = *reinterpret_cast<const uint4*>(A + (size_t)(bm + (e >> 5)) * K + kt + (e & 31));
    }
    #pragma unroll
    for (int c = 0; c < BLD; c++) {
      int e = (c * 256 + tid) * 8;
      br[c] = *reinterpret_cast<const uint4*>(W + (size_t)(bn + (e >> 5)) * K + kt + (e & 31));
    }
    __syncthreads();
    #pragma unroll
    for (int c = 0; c < ALD; c++) {
      int e = (c * 256 + tid) * 8;
      *reinterpret_cast<uint4*>(&As[e]) = ar[c];
    }
    #pragma unroll
    for (int c = 0; c < BLD; c++) {
      int e = (c * 256 + tid) * 8;
      *reinterpret_cast<uint4*>(&Ws[e]) = br[c];
    }
    __syncthreads();

    short8 af[AM], bfr[BF];
    #pragma unroll
    for (int i = 0; i < AM; i++)
      af[i] = *reinterpret_cast<const short8*>(
          &As[(wr * WM + i * 16 + (lane & 15)) * BK + (lane >> 4) * 8]);
    #pragma unroll
    for (int j = 0; j < BF; j++)
      bfr[j] = *reinterpret_cast<const short8*>(
          &Ws[(wc * WN + j * 16 + (lane & 15)) * BK + (lane >> 4) * 8]);
    #pragma unroll
    for (int i = 0; i < AM; i++)
      #pragma unroll
      for (int j = 0; j < BF; j++)
        acc[i][j] = __builtin_amdgcn_mfma_f32_16x16x32_bf16(af[i], bfr[j], acc[i][j], 0, 0, 0);
  }

  float sv = 0.f;
  if constexpr (EPI == EPI_SKIPX) sv = sscale[0];

  #pragma unroll
  for (int i = 0; i < AM; i++) {
    #pragma unroll
    for (int j = 0; j < BF; j++) {
      int row0 = bm + wr * WM + i * 16 + ((lane >> 4) << 2);
      int col  = bn + wc * WN + j * 16 + (lane & 15);
      #pragma unroll
      for (int r = 0; r < 4; r++) {
        float v = acc[i][j][r];
        size_t off = (size_t)(row0 + r) * N + col;
        if constexpr (EPI == EPI_SKIPX) v += sv * X[off];
        if constexpr (EPI == EPI_BIAS)  v += bias[col];
        C[off] = v;
      }
    }
  }
}

// ---------------- x_proj MFMA GEMM: N=48, 4 waves stacked on M --------------
__global__ __launch_bounds__(256) void gemm_mfma48(
    const unsigned short* __restrict__ A, const unsigned short* __restrict__ W,
    float* __restrict__ C, int K)
{
  __shared__ __align__(16) unsigned short As[64 * 32];
  __shared__ __align__(16) unsigned short Ws[48 * 32];
  const int tid = threadIdx.x;
  const int lane = tid & 63, wid = tid >> 6;
  const int bm = blockIdx.x * 64;
  const int e = tid * 8;
  const bool wok = tid < 192;

  f32x4 acc[3] = {};

  for (int kt = 0; kt < K; kt += 32) {
    uint4 av = *reinterpret_cast<const uint4*>(A + (size_t)(bm + (e >> 5)) * K + kt + (e & 31));
    uint4 wv2;
    if (wok) wv2 = *reinterpret_cast<const uint4*>(W + (size_t)(e >> 5) * K + kt + (e & 31));
    __syncthreads();
    *reinterpret_cast<uint4*>(&As[e]) = av;
    if (wok) *reinterpret_cast<uint4*>(&Ws[e]) = wv2;
    __syncthreads();
    short8 af = *reinterpret_cast<const short8*>(
        &As[(wid * 16 + (lane & 15)) * 32 + (lane >> 4) * 8]);
    #pragma unroll
    for (int j = 0; j < 3; j++) {
      short8 bfr = *reinterpret_cast<const short8*>(
          &Ws[(j * 16 + (lane & 15)) * 32 + (lane >> 4) * 8]);
      acc[j] = __builtin_amdgcn_mfma_f32_16x16x32_bf16(af, bfr, acc[j], 0, 0, 0);
    }
  }
  int row0 = bm + wid * 16 + ((lane >> 4) << 2);
  #pragma unroll
  for (int j = 0; j < 3; j++) {
    int col = j * 16 + (lane & 15);
    #pragma unroll
    for (int r = 0; r < 4; r++)
      C[(size_t)(row0 + r) * 48 + col] = acc[j][r];
  }
}

// ---------------- depthwise causal conv (k=4) + SiLU, f32 + bf16 out --------
__global__ __launch_bounds__(256) void conv_silu_kernel(
    const float* __restrict__ xz, const float* __restrict__ cw,
    const float* __restrict__ cb, float* __restrict__ xc,
    unsigned short* __restrict__ xc_bf)
{
  int idx = blockIdx.x * 256 + threadIdx.x;   // B*L*128
  int d4 = (idx & 127) << 2;
  int bt = idx >> 7;
  int t  = bt & (LSEQ - 1);
  int b  = bt >> 12;
  float a0 = cb[d4], a1 = cb[d4+1], a2 = cb[d4+2], a3 = cb[d4+3];
  float4 w0 = *reinterpret_cast<const float4*>(&cw[(d4+0)*4]);
  float4 w1 = *reinterpret_cast<const float4*>(&cw[(d4+1)*4]);
  float4 w2 = *reinterpret_cast<const float4*>(&cw[(d4+2)*4]);
  float4 w3 = *reinterpret_cast<const float4*>(&cw[(d4+3)*4]);
  const float* wp0 = (const float*)&w0;
  const float* wp1 = (const float*)&w1;
  const float* wp2 = (const float*)&w2;
  const float* wp3 = (const float*)&w3;
  #pragma unroll
  for (int j = 0; j < 4; j++) {
    int tt = t - 3 + j;
    if (tt >= 0) {
      float4 xv = *reinterpret_cast<const float4*>(&xz[((size_t)b*LSEQ + tt)*1024 + d4]);
      a0 += wp0[j]*xv.x; a1 += wp1[j]*xv.y; a2 += wp2[j]*xv.z; a3 += wp3[j]*xv.w;
    }
  }
  float4 o;
  o.x = a0 / (1.f + __expf(-a0));
  o.y = a1 / (1.f + __expf(-a1));
  o.z = a2 / (1.f + __expf(-a2));
  o.w = a3 / (1.f + __expf(-a3));
  size_t ro = ((size_t)b*LSEQ + t)*512 + d4;
  *reinterpret_cast<float4*>(&xc[ro]) = o;
  ushort4 ob;
  ob.x = f2bf(o.x); ob.y = f2bf(o.y); ob.z = f2bf(o.z); ob.w = f2bf(o.w);
  *reinterpret_cast<ushort4*>(&xc_bf[ro]) = ob;
}

// ---------------- dt_proj (K=16) + softplus ---------------------------------
__global__ __launch_bounds__(256) void dtproj_kernel(
    const float* __restrict__ dbc, const float* __restrict__ dpw,
    const float* __restrict__ dpb, float* __restrict__ delta)
{
  int tid = threadIdx.x;
  size_t row = (size_t)blockIdx.x * 2 + (tid >> 7);
  int d0 = (tid & 127) << 2;
  const float4* dt = reinterpret_cast<const float4*>(dbc + row * 48);
  float4 t0 = dt[0], t1 = dt[1], t2 = dt[2], t3 = dt[3];
  float4 out;
  float* op = (float*)&out;
  #pragma unroll
  for (int dd = 0; dd < 4; dd++) {
    int d = d0 + dd;
    const float4* wr = reinterpret_cast<const float4*>(&dpw[d*16]);
    float4 w0 = wr[0], w1 = wr[1], w2 = wr[2], w3 = wr[3];
    float acc = dpb[d];
    acc += t0.x*w0.x + t0.y*w0.y + t0.z*w0.z + t0.w*w0.w;
    acc += t1.x*w1.x + t1.y*w1.y + t1.z*w1.z + t1.w*w1.w;
    acc += t2.x*w2.x + t2.y*w2.y + t2.z*w2.z + t2.w*w2.w;
    acc += t3.x*w3.x + t3.y*w3.y + t3.z*w3.z + t3.w*w3.w;
    op[dd] = fmaxf(acc, 0.f) + log1pf(__expf(-fabsf(acc)));
  }
  *reinterpret_cast<float4*>(&delta[row * 512 + d0]) = out;
}

// ---------------- selective scan, chunked 3-phase, n-split x2 ---------------
// thread g: nh=g&1 (state half), d=(g>>1)&511, c=(g>>10)&(NCH-1), b=g>>18
// hloc/henter[(((c*B+b)*512+d)*16 + nh*8 + n], Ssum[(c*B+b)*512+d]
__global__ __launch_bounds__(256) void scanA_kernel(
    const float* __restrict__ delta, const float* __restrict__ xc,
    const float* __restrict__ dbc, const float* __restrict__ A_log,
    float* __restrict__ hloc, float* __restrict__ Ssum)
{
  int g = blockIdx.x * 256 + threadIdx.x;
  int nh = g & 1;
  int d  = (g >> 1) & 511;
  int c  = (g >> 10) & (NCH - 1);
  int b  = g >> 18;
  const float4* Ap = reinterpret_cast<const float4*>(A_log + d*16 + nh*8);
  float4 A0 = Ap[0], A1 = Ap[1];
  float Ar[8] = {-__expf(A0.x), -__expf(A0.y), -__expf(A0.z), -__expf(A0.w),
                 -__expf(A1.x), -__expf(A1.y), -__expf(A1.z), -__expf(A1.w)};
  float h[8] = {};
  float S = 0.f;
  size_t tbase = (size_t)b * LSEQ + (size_t)c * CL;
  for (int t = 0; t < CL; t++) {
    size_t r = tbase + t;
    float dl = delta[r*512 + d];
    float u  = xc[r*512 + d];
    float du = dl * u;
    S += dl;
    const float4* Bp = reinterpret_cast<const float4*>(dbc + r*48 + 16 + nh*8);
    float4 B0 = Bp[0], B1 = Bp[1];
    float Bv[8] = {B0.x,B0.y,B0.z,B0.w, B1.x,B1.y,B1.z,B1.w};
    #pragma unroll
    for (int n = 0; n < 8; n++)
      h[n] = __expf(dl * Ar[n]) * h[n] + du * Bv[n];
  }
  size_t o = (((size_t)c * B_SZ + b) * 512 + d) * 16 + nh*8;
  float4 h0 = {h[0],h[1],h[2],h[3]}, h1 = {h[4],h[5],h[6],h[7]};
  *reinterpret_cast<float4*>(&hloc[o])   = h0;
  *reinterpret_cast<float4*>(&hloc[o+4]) = h1;
  if (nh == 0) Ssum[((size_t)c * B_SZ + b) * 512 + d] = S;
}

// one thread per (b,d,n) state component; fully coalesced over (d,n)
__global__ __launch_bounds__(256) void scanmid2_kernel(
    const float* __restrict__ hloc, const float* __restrict__ Ssum,
    const float* __restrict__ A_log, float* __restrict__ henter)
{
  int g = blockIdx.x * 256 + threadIdx.x;   // B*512*16 = 16384
  int n = g & 15, d = (g >> 4) & 511, b = g >> 13;
  float Ar = -__expf(A_log[d*16 + n]);
  float h = 0.f;
  #pragma unroll 4
  for (int c = 0; c < NCH; c++) {
    size_t idx = ((size_t)c * B_SZ + b) * 512 + d;
    henter[idx*16 + n] = h;
    h = __expf(Ssum[idx] * Ar) * h + hloc[idx*16 + n];
  }
}

__global__ __launch_bounds__(256) void scanB_kernel(
    const float* __restrict__ delta, const float* __restrict__ xc,
    const float* __restrict__ dbc, const float* __restrict__ A_log,
    const float* __restrict__ henter, const float* __restrict__ Dskip,
    const float* __restrict__ xz, unsigned short* __restrict__ y_bf)
{
  int g = blockIdx.x * 256 + threadIdx.x;
  int nh = g & 1;
  int d  = (g >> 1) & 511;
  int c  = (g >> 10) & (NCH - 1);
  int b  = g >> 18;
  const float4* Ap = reinterpret_cast<const float4*>(A_log + d*16 + nh*8);
  float4 A0 = Ap[0], A1 = Ap[1];
  float Ar[8] = {-__expf(A0.x), -__expf(A0.y), -__expf(A0.z), -__expf(A0.w),
                 -__expf(A1.x), -__expf(A1.y), -__expf(A1.z), -__expf(A1.w)};
  size_t o = (((size_t)c * B_SZ + b) * 512 + d) * 16 + nh*8;
  float4 h0 = *reinterpret_cast<const float4*>(&henter[o]);
  float4 h1 = *reinterpret_cast<const float4*>(&henter[o+4]);
  float h[8] = {h0.x,h0.y,h0.z,h0.w, h1.x,h1.y,h1.z,h1.w};
  float Dsk = Dskip[d];
  size_t tbase = (size_t)b * LSEQ + (size_t)c * CL;
  for (int t = 0; t < CL; t++) {
    size_t r = tbase + t;
    float dl = delta[r*512 + d];
    float u  = xc[r*512 + d];
    float du = dl * u;
    const float4* Bp = reinterpret_cast<const float4*>(dbc + r*48 + 16 + nh*8);
    const float4* Cp = reinterpret_cast<const float4*>(dbc + r*48 + 32 + nh*8);
    float4 B0 = Bp[0], B1 = Bp[1];
    float4 C0 = Cp[0], C1 = Cp[1];
    float Bv[8] = {B0.x,B0.y,B0.z,B0.w, B1.x,B1.y,B1.z,B1.w};
    float Cv[8] = {C0.x,C0.y,C0.z,C0.w, C1.x,C1.y,C1.z,C1.w};
    float yp = 0.f;
    #pragma unroll
    for (int n = 0; n < 8; n++) {
      h[n] = __expf(dl * Ar[n]) * h[n] + du * Bv[n];
      yp += h[n] * Cv[n];
    }
    float y = yp + __shfl_xor(yp, 1);
    if (nh == 0) {
      y += u * Dsk;
      float z = xz[r*1024 + 512 + d];
      float sig = 1.f / (1.f + __expf(-z));
      y_bf[r*512 + d] = f2bf(y * z * sig);
    }
  }
}

// ---------------- launch ----------------------------------------------------
extern "C" void kernel_launch(void* const* d_in, const int* in_sizes, int n_in,
                              void* d_out, int out_size, void* d_ws, size_t ws_size,
                              hipStream_t stream)
{
  const float* x      = (const float*)d_in[0];
  const float* ln_w   = (const float*)d_in[1];
  const float* ln_b   = (const float*)d_in[2];
  const float* inW    = (const float*)d_in[3];
  const float* convW  = (const float*)d_in[4];
  const float* convB  = (const float*)d_in[5];
  const float* xprojW = (const float*)d_in[6];
  const float* dtW    = (const float*)d_in[7];
  const float* dtB    = (const float*)d_in[8];
  const float* A_log  = (const float*)d_in[9];
  const float* Dskip  = (const float*)d_in[10];
  const float* outW   = (const float*)d_in[11];
  const float* projW  = (const float*)d_in[12];
  const float* projB  = (const float*)d_in[13];
  const float* skip   = (const float*)d_in[14];
  float* out = (float*)d_out;

  const size_t BL = (size_t)B_SZ * LSEQ;   // 8192
  char* p = (char*)d_ws;
  unsigned short* xn_bf = (unsigned short*)p;  p += BL*256*2;
  float* xz     = (float*)p;                   p += BL*1024*4;
  float* xc     = (float*)p;                   p += BL*512*4;
  float* dbc    = (float*)p;                   p += BL*48*4;
  float* delta  = (float*)p;                   p += BL*512*4;
  float* hloc   = (float*)p;                   p += (size_t)NCH*B_SZ*512*16*4;
  float* henter = (float*)p;                   p += (size_t)NCH*B_SZ*512*16*4;
  float* Ssum   = (float*)p;                   p += (size_t)NCH*B_SZ*512*4;
  unsigned short* y_bf = (unsigned short*)p;   p += BL*512*2;
  unsigned short* inW_bf  = (unsigned short*)p; p += 1024*256*2;
  unsigned short* outW_bf = (unsigned short*)p; p += 256*512*2;
  unsigned short* projW_bf= (unsigned short*)p; p += 256*256*2;
  unsigned short* xprojW_bf=(unsigned short*)p; p += 48*512*2;
  // overlays (disjoint lifetimes):
  unsigned short* xc_bf = (unsigned short*)henter; // dead before scanmid writes henter
  float* xm = hloc;                 // born after scanmid (hloc dead)
  unsigned short* xn2_bf = xn_bf;   // xn_bf dead after in_proj

  f2bf4_kernel<<<1024*256/1024, 256, 0, stream>>>(inW,  inW_bf);
  f2bf4_kernel<<<256*512/1024, 256, 0, stream>>>(outW, outW_bf);
  f2bf4_kernel<<<256*256/1024, 256, 0, stream>>>(projW, projW_bf);
  f2bf4_kernel<<<48*512/1024, 256, 0, stream>>>(xprojW, xprojW_bf);

  ln_bf_kernel<<<BL/4, 256, 0, stream>>>(x, ln_w, ln_b, xn_bf);

  gemm_mfma<128,128,EPI_NONE><<<dim3(BL/128, 1024/128), 256, 0, stream>>>(
      xn_bf, inW_bf, xz, (int)BL, 1024, 256, nullptr, nullptr, nullptr);

  conv_silu_kernel<<<(B_SZ*LSEQ*128)/256, 256, 0, stream>>>(xz, convW, convB, xc, xc_bf);

  gemm_mfma48<<<BL/64, 256, 0, stream>>>(xc_bf, xprojW_bf, dbc, 512);

  dtproj_kernel<<<BL/2, 256, 0, stream>>>(dbc, dtW, dtB, delta);

  scanA_kernel<<<(B_SZ*NCH*512*2)/256, 256, 0, stream>>>(delta, xc, dbc, A_log, hloc, Ssum);
  scanmid2_kernel<<<B_SZ*512*16/256, 256, 0, stream>>>(hloc, Ssum, A_log, henter);
  scanB_kernel<<<(B_SZ*NCH*512*2)/256, 256, 0, stream>>>(delta, xc, dbc, A_log, henter, Dskip, xz, y_bf);

  gemm_mfma<128,64,EPI_SKIPX><<<dim3(BL/128, 256/64), 256, 0, stream>>>(
      y_bf, outW_bf, xm, (int)BL, 256, 512, x, skip, nullptr);

  ln_bf_kernel<<<BL/4, 256, 0, stream>>>(xm, ln_w, ln_b, xn2_bf);

  gemm_mfma<128,64,EPI_BIAS><<<dim3(BL/128, 256/64), 256, 0, stream>>>(
      xn2_bf, projW_bf, out, (int)BL, 256, 256, nullptr, nullptr, projB);
}

// Round 4
// 263.268 us; speedup vs baseline: 2.3084x; 1.2813x over previous
//
#include <hip/hip_runtime.h>
#include <hip/hip_bf16.h>

#define B_SZ   2
#define LSEQ   4096
#define NCH    256
#define CL     16

typedef __attribute__((ext_vector_type(8))) short short8;
typedef __attribute__((ext_vector_type(4))) float f32x4;

__device__ __forceinline__ unsigned short f2bf(float f) {
  union { float f; unsigned u; } x; x.f = f;
  unsigned r = x.u + 0x7fffu + ((x.u >> 16) & 1u);
  return (unsigned short)(r >> 16);
}

// global->LDS direct async copy, 16B per lane; l must be wave-uniform base.
__device__ __forceinline__ void gload_lds16(const unsigned short* g, unsigned short* l) {
  __builtin_amdgcn_global_load_lds(
      (const __attribute__((address_space(1))) unsigned int*)g,
      (__attribute__((address_space(3))) unsigned int*)l, 16, 0, 0);
}

// ---------------- weight fp32 -> bf16 convert -------------------------------
__global__ __launch_bounds__(256) void f2bf4_kernel(
    const float* __restrict__ in, unsigned short* __restrict__ out)
{
  int i = (blockIdx.x * 256 + threadIdx.x) * 4;
  float4 v = *reinterpret_cast<const float4*>(in + i);
  ushort4 o;
  o.x = f2bf(v.x); o.y = f2bf(v.y); o.z = f2bf(v.z); o.w = f2bf(v.w);
  *reinterpret_cast<ushort4*>(out + i) = o;
}

// ---------------- LayerNorm: one wave per 256-float row, bf16 out -----------
__global__ __launch_bounds__(256) void ln_bf_kernel(
    const float* __restrict__ in, const float* __restrict__ w,
    const float* __restrict__ b, unsigned short* __restrict__ out)
{
  int wv = threadIdx.x >> 6, lane = threadIdx.x & 63;
  size_t row = (size_t)blockIdx.x * 4 + wv;
  float4 v = reinterpret_cast<const float4*>(in)[row * 64 + lane];
  float s  = v.x + v.y + v.z + v.w;
  float sq = v.x*v.x + v.y*v.y + v.z*v.z + v.w*v.w;
  #pragma unroll
  for (int off = 32; off; off >>= 1) {
    s  += __shfl_xor(s,  off);
    sq += __shfl_xor(sq, off);
  }
  float mu  = s * (1.f/256.f);
  float var = sq * (1.f/256.f) - mu*mu;
  float rs  = rsqrtf(var + 1e-5f);
  float4 wv4 = reinterpret_cast<const float4*>(w)[lane];
  float4 bv4 = reinterpret_cast<const float4*>(b)[lane];
  ushort4 o;
  o.x = f2bf((v.x-mu)*rs*wv4.x + bv4.x);
  o.y = f2bf((v.y-mu)*rs*wv4.y + bv4.y);
  o.z = f2bf((v.z-mu)*rs*wv4.z + bv4.z);
  o.w = f2bf((v.w-mu)*rs*wv4.w + bv4.w);
  reinterpret_cast<ushort4*>(out)[row * 64 + lane] = o;
}

// ------ bf16 MFMA GEMM, global_load_lds + dbuf pipeline: C = A * W^T --------
enum { EPI_NONE = 0, EPI_SKIPX = 1, EPI_BIAS = 2 };

template<int BM, int BN, int EPI>
__global__ __launch_bounds__(256) void gemm_mfma(
    const unsigned short* __restrict__ A, const unsigned short* __restrict__ W,
    float* __restrict__ C, int M, int N, int K,
    const float* __restrict__ X, const float* __restrict__ sscale,
    const float* __restrict__ bias)
{
  constexpr int BK = 32;
  constexpr int WM = BM / 2, WN = BN / 2;       // 2x2 waves
  constexpr int AM = WM / 16, BF = WN / 16;
  constexpr int AI = BM / 64, BI = BN / 64;     // stage instrs per wave
  __shared__ __align__(16) unsigned short As[2][BM * BK];
  __shared__ __align__(16) unsigned short Ws[2][BN * BK];
  const int tid = threadIdx.x, lane = tid & 63, wid = tid >> 6;
  const int wr = wid >> 1, wc = wid & 1;
  const int bm = blockIdx.x * BM, bn = blockIdx.y * BN;
  const int srow = lane >> 2;          // row within 16-row group
  const int skoff = (lane & 3) * 8;    // bf16 col offset

  f32x4 acc[AM][BF] = {};

  auto stage = [&](int buf, int kt) {
    #pragma unroll
    for (int i = 0; i < AI; i++) {
      int rowg = (wid * AI + i) * 16;
      gload_lds16(A + (size_t)(bm + rowg + srow) * K + kt + skoff,
                  &As[buf][rowg * BK]);
    }
    #pragma unroll
    for (int i = 0; i < BI; i++) {
      int rowg = (wid * BI + i) * 16;
      gload_lds16(W + (size_t)(bn + rowg + srow) * K + kt + skoff,
                  &Ws[buf][rowg * BK]);
    }
  };

  stage(0, 0);
  __syncthreads();
  const int nt = K / BK;
  int cur = 0;
  for (int t = 0; t < nt; t++) {
    if (t + 1 < nt) stage(cur ^ 1, (t + 1) * BK);
    short8 af[AM], bfr[BF];
    #pragma unroll
    for (int i = 0; i < AM; i++)
      af[i] = *reinterpret_cast<const short8*>(
          &As[cur][(wr * WM + i * 16 + (lane & 15)) * BK + (lane >> 4) * 8]);
    #pragma unroll
    for (int j = 0; j < BF; j++)
      bfr[j] = *reinterpret_cast<const short8*>(
          &Ws[cur][(wc * WN + j * 16 + (lane & 15)) * BK + (lane >> 4) * 8]);
    #pragma unroll
    for (int i = 0; i < AM; i++)
      #pragma unroll
      for (int j = 0; j < BF; j++)
        acc[i][j] = __builtin_amdgcn_mfma_f32_16x16x32_bf16(af[i], bfr[j], acc[i][j], 0, 0, 0);
    __syncthreads();     // drains stage loads (vmcnt) + LDS reads, once per K-step
    cur ^= 1;
  }

  float sv = 0.f;
  if constexpr (EPI == EPI_SKIPX) sv = sscale[0];

  #pragma unroll
  for (int i = 0; i < AM; i++) {
    #pragma unroll
    for (int j = 0; j < BF; j++) {
      int row0 = bm + wr * WM + i * 16 + ((lane >> 4) << 2);
      int col  = bn + wc * WN + j * 16 + (lane & 15);
      #pragma unroll
      for (int r = 0; r < 4; r++) {
        float v = acc[i][j][r];
        size_t off = (size_t)(row0 + r) * N + col;
        if constexpr (EPI == EPI_SKIPX) v += sv * X[off];
        if constexpr (EPI == EPI_BIAS)  v += bias[col];
        C[off] = v;
      }
    }
  }
}

// ---------------- x_proj MFMA GEMM: N=48, pipelined -------------------------
__global__ __launch_bounds__(256) void gemm_mfma48(
    const unsigned short* __restrict__ A, const unsigned short* __restrict__ W,
    float* __restrict__ C, int K)
{
  __shared__ __align__(16) unsigned short As[2][64 * 32];
  __shared__ __align__(16) unsigned short Ws[2][48 * 32];
  const int tid = threadIdx.x, lane = tid & 63, wid = tid >> 6;
  const int bm = blockIdx.x * 64;
  const int srow = lane >> 2, skoff = (lane & 3) * 8;

  f32x4 acc[3] = {};

  auto stage = [&](int buf, int kt) {
    int rowg = wid * 16;
    gload_lds16(A + (size_t)(bm + rowg + srow) * K + kt + skoff, &As[buf][rowg * 32]);
    if (wid < 3)
      gload_lds16(W + (size_t)(rowg + srow) * K + kt + skoff, &Ws[buf][rowg * 32]);
  };

  stage(0, 0);
  __syncthreads();
  const int nt = K / 32;
  int cur = 0;
  for (int t = 0; t < nt; t++) {
    if (t + 1 < nt) stage(cur ^ 1, (t + 1) * 32);
    short8 af = *reinterpret_cast<const short8*>(
        &As[cur][(wid * 16 + (lane & 15)) * 32 + (lane >> 4) * 8]);
    #pragma unroll
    for (int j = 0; j < 3; j++) {
      short8 bfr = *reinterpret_cast<const short8*>(
          &Ws[cur][(j * 16 + (lane & 15)) * 32 + (lane >> 4) * 8]);
      acc[j] = __builtin_amdgcn_mfma_f32_16x16x32_bf16(af, bfr, acc[j], 0, 0, 0);
    }
    __syncthreads();
    cur ^= 1;
  }
  int row0 = bm + wid * 16 + ((lane >> 4) << 2);
  #pragma unroll
  for (int j = 0; j < 3; j++) {
    int col = j * 16 + (lane & 15);
    #pragma unroll
    for (int r = 0; r < 4; r++)
      C[(size_t)(row0 + r) * 48 + col] = acc[j][r];
  }
}

// ---------------- depthwise causal conv (k=4) + SiLU, f32 + bf16 out --------
__global__ __launch_bounds__(256) void conv_silu_kernel(
    const float* __restrict__ xz, const float* __restrict__ cw,
    const float* __restrict__ cb, float* __restrict__ xc,
    unsigned short* __restrict__ xc_bf)
{
  int idx = blockIdx.x * 256 + threadIdx.x;   // B*L*128
  int d4 = (idx & 127) << 2;
  int bt = idx >> 7;
  int t  = bt & (LSEQ - 1);
  int b  = bt >> 12;
  float a0 = cb[d4], a1 = cb[d4+1], a2 = cb[d4+2], a3 = cb[d4+3];
  float4 w0 = *reinterpret_cast<const float4*>(&cw[(d4+0)*4]);
  float4 w1 = *reinterpret_cast<const float4*>(&cw[(d4+1)*4]);
  float4 w2 = *reinterpret_cast<const float4*>(&cw[(d4+2)*4]);
  float4 w3 = *reinterpret_cast<const float4*>(&cw[(d4+3)*4]);
  const float* wp0 = (const float*)&w0;
  const float* wp1 = (const float*)&w1;
  const float* wp2 = (const float*)&w2;
  const float* wp3 = (const float*)&w3;
  #pragma unroll
  for (int j = 0; j < 4; j++) {
    int tt = t - 3 + j;
    if (tt >= 0) {
      float4 xv = *reinterpret_cast<const float4*>(&xz[((size_t)b*LSEQ + tt)*1024 + d4]);
      a0 += wp0[j]*xv.x; a1 += wp1[j]*xv.y; a2 += wp2[j]*xv.z; a3 += wp3[j]*xv.w;
    }
  }
  float4 o;
  o.x = a0 / (1.f + __expf(-a0));
  o.y = a1 / (1.f + __expf(-a1));
  o.z = a2 / (1.f + __expf(-a2));
  o.w = a3 / (1.f + __expf(-a3));
  size_t ro = ((size_t)b*LSEQ + t)*512 + d4;
  *reinterpret_cast<float4*>(&xc[ro]) = o;
  ushort4 ob;
  ob.x = f2bf(o.x); ob.y = f2bf(o.y); ob.z = f2bf(o.z); ob.w = f2bf(o.w);
  *reinterpret_cast<ushort4*>(&xc_bf[ro]) = ob;
}

// ---------------- dt_proj (K=16) + softplus ---------------------------------
__global__ __launch_bounds__(256) void dtproj_kernel(
    const float* __restrict__ dbc, const float* __restrict__ dpw,
    const float* __restrict__ dpb, float* __restrict__ delta)
{
  int tid = threadIdx.x;
  size_t row = (size_t)blockIdx.x * 2 + (tid >> 7);
  int d0 = (tid & 127) << 2;
  const float4* dt = reinterpret_cast<const float4*>(dbc + row * 48);
  float4 t0 = dt[0], t1 = dt[1], t2 = dt[2], t3 = dt[3];
  float4 out;
  float* op = (float*)&out;
  #pragma unroll
  for (int dd = 0; dd < 4; dd++) {
    int d = d0 + dd;
    const float4* wr = reinterpret_cast<const float4*>(&dpw[d*16]);
    float4 w0 = wr[0], w1 = wr[1], w2 = wr[2], w3 = wr[3];
    float acc = dpb[d];
    acc += t0.x*w0.x + t0.y*w0.y + t0.z*w0.z + t0.w*w0.w;
    acc += t1.x*w1.x + t1.y*w1.y + t1.z*w1.z + t1.w*w1.w;
    acc += t2.x*w2.x + t2.y*w2.y + t2.z*w2.z + t2.w*w2.w;
    acc += t3.x*w3.x + t3.y*w3.y + t3.z*w3.z + t3.w*w3.w;
    op[dd] = fmaxf(acc, 0.f) + log1pf(__expf(-fabsf(acc)));
  }
  *reinterpret_cast<float4*>(&delta[row * 512 + d0]) = out;
}

// ---------------- selective scan, chunked 3-phase, n-split x2 ---------------
__global__ __launch_bounds__(256) void scanA_kernel(
    const float* __restrict__ delta, const float* __restrict__ xc,
    const float* __restrict__ dbc, const float* __restrict__ A_log,
    float* __restrict__ hloc, float* __restrict__ Ssum)
{
  int g = blockIdx.x * 256 + threadIdx.x;
  int nh = g & 1;
  int d  = (g >> 1) & 511;
  int c  = (g >> 10) & (NCH - 1);
  int b  = g >> 18;
  const float4* Ap = reinterpret_cast<const float4*>(A_log + d*16 + nh*8);
  float4 A0 = Ap[0], A1 = Ap[1];
  float Ar[8] = {-__expf(A0.x), -__expf(A0.y), -__expf(A0.z), -__expf(A0.w),
                 -__expf(A1.x), -__expf(A1.y), -__expf(A1.z), -__expf(A1.w)};
  float h[8] = {};
  float S = 0.f;
  size_t tbase = (size_t)b * LSEQ + (size_t)c * CL;
  for (int t = 0; t < CL; t++) {
    size_t r = tbase + t;
    float dl = delta[r*512 + d];
    float u  = xc[r*512 + d];
    float du = dl * u;
    S += dl;
    const float4* Bp = reinterpret_cast<const float4*>(dbc + r*48 + 16 + nh*8);
    float4 B0 = Bp[0], B1 = Bp[1];
    float Bv[8] = {B0.x,B0.y,B0.z,B0.w, B1.x,B1.y,B1.z,B1.w};
    #pragma unroll
    for (int n = 0; n < 8; n++)
      h[n] = __expf(dl * Ar[n]) * h[n] + du * Bv[n];
  }
  size_t o = (((size_t)c * B_SZ + b) * 512 + d) * 16 + nh*8;
  float4 h0 = {h[0],h[1],h[2],h[3]}, h1 = {h[4],h[5],h[6],h[7]};
  *reinterpret_cast<float4*>(&hloc[o])   = h0;
  *reinterpret_cast<float4*>(&hloc[o+4]) = h1;
  if (nh == 0) Ssum[((size_t)c * B_SZ + b) * 512 + d] = S;
}

__global__ __launch_bounds__(256) void scanmid2_kernel(
    const float* __restrict__ hloc, const float* __restrict__ Ssum,
    const float* __restrict__ A_log, float* __restrict__ henter)
{
  int g = blockIdx.x * 256 + threadIdx.x;   // B*512*16 = 16384
  int n = g & 15, d = (g >> 4) & 511, b = g >> 13;
  float Ar = -__expf(A_log[d*16 + n]);
  float h = 0.f;
  #pragma unroll 4
  for (int c = 0; c < NCH; c++) {
    size_t idx = ((size_t)c * B_SZ + b) * 512 + d;
    henter[idx*16 + n] = h;
    h = __expf(Ssum[idx] * Ar) * h + hloc[idx*16 + n];
  }
}

__global__ __launch_bounds__(256) void scanB_kernel(
    const float* __restrict__ delta, const float* __restrict__ xc,
    const float* __restrict__ dbc, const float* __restrict__ A_log,
    const float* __restrict__ henter, const float* __restrict__ Dskip,
    const float* __restrict__ xz, unsigned short* __restrict__ y_bf)
{
  int g = blockIdx.x * 256 + threadIdx.x;
  int nh = g & 1;
  int d  = (g >> 1) & 511;
  int c  = (g >> 10) & (NCH - 1);
  int b  = g >> 18;
  const float4* Ap = reinterpret_cast<const float4*>(A_log + d*16 + nh*8);
  float4 A0 = Ap[0], A1 = Ap[1];
  float Ar[8] = {-__expf(A0.x), -__expf(A0.y), -__expf(A0.z), -__expf(A0.w),
                 -__expf(A1.x), -__expf(A1.y), -__expf(A1.z), -__expf(A1.w)};
  size_t o = (((size_t)c * B_SZ + b) * 512 + d) * 16 + nh*8;
  float4 h0 = *reinterpret_cast<const float4*>(&henter[o]);
  float4 h1 = *reinterpret_cast<const float4*>(&henter[o+4]);
  float h[8] = {h0.x,h0.y,h0.z,h0.w, h1.x,h1.y,h1.z,h1.w};
  float Dsk = Dskip[d];
  size_t tbase = (size_t)b * LSEQ + (size_t)c * CL;
  for (int t = 0; t < CL; t++) {
    size_t r = tbase + t;
    float dl = delta[r*512 + d];
    float u  = xc[r*512 + d];
    float du = dl * u;
    const float4* Bp = reinterpret_cast<const float4*>(dbc + r*48 + 16 + nh*8);
    const float4* Cp = reinterpret_cast<const float4*>(dbc + r*48 + 32 + nh*8);
    float4 B0 = Bp[0], B1 = Bp[1];
    float4 C0 = Cp[0], C1 = Cp[1];
    float Bv[8] = {B0.x,B0.y,B0.z,B0.w, B1.x,B1.y,B1.z,B1.w};
    float Cv[8] = {C0.x,C0.y,C0.z,C0.w, C1.x,C1.y,C1.z,C1.w};
    float yp = 0.f;
    #pragma unroll
    for (int n = 0; n < 8; n++) {
      h[n] = __expf(dl * Ar[n]) * h[n] + du * Bv[n];
      yp += h[n] * Cv[n];
    }
    float y = yp + __shfl_xor(yp, 1);
    if (nh == 0) {
      y += u * Dsk;
      float z = xz[r*1024 + 512 + d];
      float sig = 1.f / (1.f + __expf(-z));
      y_bf[r*512 + d] = f2bf(y * z * sig);
    }
  }
}

// ---------------- launch ----------------------------------------------------
extern "C" void kernel_launch(void* const* d_in, const int* in_sizes, int n_in,
                              void* d_out, int out_size, void* d_ws, size_t ws_size,
                              hipStream_t stream)
{
  const float* x      = (const float*)d_in[0];
  const float* ln_w   = (const float*)d_in[1];
  const float* ln_b   = (const float*)d_in[2];
  const float* inW    = (const float*)d_in[3];
  const float* convW  = (const float*)d_in[4];
  const float* convB  = (const float*)d_in[5];
  const float* xprojW = (const float*)d_in[6];
  const float* dtW    = (const float*)d_in[7];
  const float* dtB    = (const float*)d_in[8];
  const float* A_log  = (const float*)d_in[9];
  const float* Dskip  = (const float*)d_in[10];
  const float* outW   = (const float*)d_in[11];
  const float* projW  = (const float*)d_in[12];
  const float* projB  = (const float*)d_in[13];
  const float* skip   = (const float*)d_in[14];
  float* out = (float*)d_out;

  const size_t BL = (size_t)B_SZ * LSEQ;   // 8192
  char* p = (char*)d_ws;
  unsigned short* xn_bf = (unsigned short*)p;  p += BL*256*2;
  float* xz     = (float*)p;                   p += BL*1024*4;
  float* xc     = (float*)p;                   p += BL*512*4;
  float* dbc    = (float*)p;                   p += BL*48*4;
  float* delta  = (float*)p;                   p += BL*512*4;
  float* hloc   = (float*)p;                   p += (size_t)NCH*B_SZ*512*16*4;
  float* henter = (float*)p;                   p += (size_t)NCH*B_SZ*512*16*4;
  float* Ssum   = (float*)p;                   p += (size_t)NCH*B_SZ*512*4;
  unsigned short* y_bf = (unsigned short*)p;   p += BL*512*2;
  unsigned short* inW_bf  = (unsigned short*)p; p += 1024*256*2;
  unsigned short* outW_bf = (unsigned short*)p; p += 256*512*2;
  unsigned short* projW_bf= (unsigned short*)p; p += 256*256*2;
  unsigned short* xprojW_bf=(unsigned short*)p; p += 48*512*2;
  // overlays (disjoint lifetimes):
  unsigned short* xc_bf = (unsigned short*)henter; // dead before scanmid writes henter
  float* xm = hloc;                 // born after scanmid (hloc dead)
  unsigned short* xn2_bf = xn_bf;   // xn_bf dead after in_proj

  f2bf4_kernel<<<1024*256/1024, 256, 0, stream>>>(inW,  inW_bf);
  f2bf4_kernel<<<256*512/1024, 256, 0, stream>>>(outW, outW_bf);
  f2bf4_kernel<<<256*256/1024, 256, 0, stream>>>(projW, projW_bf);
  f2bf4_kernel<<<48*512/1024, 256, 0, stream>>>(xprojW, xprojW_bf);

  ln_bf_kernel<<<BL/4, 256, 0, stream>>>(x, ln_w, ln_b, xn_bf);

  gemm_mfma<128,128,EPI_NONE><<<dim3(BL/128, 1024/128), 256, 0, stream>>>(
      xn_bf, inW_bf, xz, (int)BL, 1024, 256, nullptr, nullptr, nullptr);

  conv_silu_kernel<<<(B_SZ*LSEQ*128)/256, 256, 0, stream>>>(xz, convW, convB, xc, xc_bf);

  gemm_mfma48<<<BL/64, 256, 0, stream>>>(xc_bf, xprojW_bf, dbc, 512);

  dtproj_kernel<<<BL/2, 256, 0, stream>>>(dbc, dtW, dtB, delta);

  scanA_kernel<<<(B_SZ*NCH*512*2)/256, 256, 0, stream>>>(delta, xc, dbc, A_log, hloc, Ssum);
  scanmid2_kernel<<<B_SZ*512*16/256, 256, 0, stream>>>(hloc, Ssum, A_log, henter);
  scanB_kernel<<<(B_SZ*NCH*512*2)/256, 256, 0, stream>>>(delta, xc, dbc, A_log, henter, Dskip, xz, y_bf);

  gemm_mfma<64,64,EPI_SKIPX><<<dim3(BL/64, 256/64), 256, 0, stream>>>(
      y_bf, outW_bf, xm, (int)BL, 256, 512, x, skip, nullptr);

  ln_bf_kernel<<<BL/4, 256, 0, stream>>>(xm, ln_w, ln_b, xn2_bf);

  gemm_mfma<64,64,EPI_BIAS><<<dim3(BL/64, 256/64), 256, 0, stream>>>(
      xn2_bf, projW_bf, out, (int)BL, 256, 256, nullptr, nullptr, projB);
}